// Round 5
// baseline (859.653 us; speedup 1.0000x reference)
//
#include <hip/hip_runtime.h>
#include <hip/hip_bf16.h>
#include <math.h>

// Problem constants (fixed by reference setup_inputs)
constexpr int NROWS = 8192;   // B
constexpr int HDIM  = 256;    // H (= K of the GEMM)
constexpr int N2    = 16384;  // 2*B rows of Z
constexpr int BM    = 128;    // tile M = tile N
constexpr int BK    = 32;     // K chunk staged per round (8 chunks)
constexpr int NCHUNK = HDIM / BK;     // 8
constexpr int NTILE = N2 / BM;        // 128 tile-rows
constexpr int NBLK  = NTILE * (NTILE + 1) / 2;  // 8256 upper-tri tiles

// sqrt(2 * log2(e)): Z pre-scaled so Zs_i.Zs_j = 2*log2(e)*cos and
// exp2(acc) == exp(sim/tau), tau = 0.5
constexpr float PRESCALE = 1.69864357f;

typedef __attribute__((ext_vector_type(4))) float floatx4;
typedef __attribute__((ext_vector_type(8))) short shortx8; // 8 bf16 = 4 VGPRs

// offset must be a literal; constant pointer adds fold into the insn's
// immediate offset field after unrolling.
__device__ __forceinline__ void async_copy16(const void* gptr, void* lptr) {
    __builtin_amdgcn_global_load_lds(
        (const __attribute__((address_space(1))) unsigned int*)gptr,
        (__attribute__((address_space(3))) unsigned int*)lptr, 16, 0, 0);
}

// s_waitcnt immediates (gfx9: vm[3:0], exp[6:4], lgkm[11:8])
#define WAIT_VM4()   __builtin_amdgcn_s_waitcnt(0x0F74)  // vmcnt(4), others free
#define WAIT_VM0()   __builtin_amdgcn_s_waitcnt(0x0F70)  // vmcnt(0), others free
#define WAIT_LGKM0() __builtin_amdgcn_s_waitcnt(0xC07F)  // lgkmcnt(0), vm free
#define MEMFENCE()   __asm__ __volatile__("" ::: "memory")
#define RAW_BARRIER() do { MEMFENCE(); __builtin_amdgcn_s_barrier(); MEMFENCE(); } while (0)

// ---------------------------------------------------------------------------
// Kernel 1: wave-per-row L2-normalize -> bf16 Z (pre-scaled); pos = cos(x,y).
// Also zeroes rowsum and the done-counter (stream-ordered before simgemm).
// ---------------------------------------------------------------------------
__global__ __launch_bounds__(256) void normalize_kernel(
    const float* __restrict__ x, const float* __restrict__ y,
    __hip_bfloat16* __restrict__ Z, float* __restrict__ pos,
    float* __restrict__ rowsum, int* __restrict__ counter)
{
    const int wave = threadIdx.x >> 6, lane = threadIdx.x & 63;
    const int row  = blockIdx.x * 4 + wave;           // grid 2048 -> 8192 rows

    const float4 xv = ((const float4*)x)[row * 64 + lane];
    const float4 yv = ((const float4*)y)[row * 64 + lane];

    float sx  = xv.x*xv.x + xv.y*xv.y + xv.z*xv.z + xv.w*xv.w;
    float sy  = yv.x*yv.x + yv.y*yv.y + yv.z*yv.z + yv.w*yv.w;
    float sxy = xv.x*yv.x + xv.y*yv.y + xv.z*yv.z + xv.w*yv.w;
    #pragma unroll
    for (int m = 1; m < 64; m <<= 1) {
        sx  += __shfl_xor(sx,  m);
        sy  += __shfl_xor(sy,  m);
        sxy += __shfl_xor(sxy, m);
    }
    const float rxn = rsqrtf(sx), ryn = rsqrtf(sy);
    const float rx = rxn * PRESCALE, ry = ryn * PRESCALE;

    union { ushort4 u; __hip_bfloat16 h[4]; } zx, zy;
    zx.h[0] = __float2bfloat16(xv.x * rx); zx.h[1] = __float2bfloat16(xv.y * rx);
    zx.h[2] = __float2bfloat16(xv.z * rx); zx.h[3] = __float2bfloat16(xv.w * rx);
    zy.h[0] = __float2bfloat16(yv.x * ry); zy.h[1] = __float2bfloat16(yv.y * ry);
    zy.h[2] = __float2bfloat16(yv.z * ry); zy.h[3] = __float2bfloat16(yv.w * ry);
    ((ushort4*)Z)[row * 64 + lane]             = zx.u;
    ((ushort4*)Z)[(row + NROWS) * 64 + lane]   = zy.u;

    if (lane == 0) {
        const float p = sxy * rxn * ryn;
        pos[row]         = p;
        pos[row + NROWS] = p;
    }
    const int gt = blockIdx.x * 256 + threadIdx.x;
    if (gt < N2) rowsum[gt] = 0.f;
    if (gt == 0) *counter = 0;
}

// ---------------------------------------------------------------------------
// Kernel 2: upper-triangle tiled Z·Z^T, fused exp2 + row/col sums + final
// loss reduction (last-finisher block). BK=32 double-buffered staging:
// LDS = 33 KB -> 4 blocks/CU (16 waves) AND prefetch via raw barrier +
// vmcnt(4) (next chunk's 4 loads stay in flight across the barrier).
// All global_load_lds / ds_read offsets are compile-time immediates off a
// single per-lane base address -> near-zero per-chunk VALU.
// LDS tile layout: row-major [128][32] bf16 per tile; 16B chunk c of row r
// stored at chunk c ^ ((r>>1)&3)  (frag reads then 2-way max = free).
// ---------------------------------------------------------------------------
__global__ __launch_bounds__(256, 4) void simgemm_kernel(
    const __hip_bfloat16* __restrict__ Z, float* __restrict__ rowsum,
    const float* __restrict__ pos, int* __restrict__ counter,
    float* __restrict__ out)
{
    // linear -> (bi, bj) upper-triangle mapping; cum(bi) = bi*(257-bi)/2
    const int b = blockIdx.x;
    int bi = (int)((257.0f - sqrtf(66049.0f - 8.0f * (float)b)) * 0.5f);
    int cum = bi * (257 - bi) / 2;
    if (b < cum)      { bi--; cum = bi * (257 - bi) / 2; }
    else { const int cn = (bi + 1) * (256 - bi) / 2;
           if (b >= cn) { bi++; cum = cn; } }
    const int bj = bi + (b - cum);
    const bool diag = (bi == bj);

    // contiguous LDS: tA[2] | tB[2] (8 KB each) | rs | cs
    __shared__ alignas(16) __hip_bfloat16 tiles[4 * BM * BK];  // 32 KB
    __shared__ float rs[BM];
    __shared__ float cs[BM];
    __hip_bfloat16* tA = tiles;                 // +0, buf1 at +8192 B
    __hip_bfloat16* tB = tiles + 2 * BM * BK;   // +16384 B, buf1 +24576 B

    const int tid  = threadIdx.x;
    const int wave = tid >> 6;
    const int lane = tid & 63;
    const int wm   = wave & 1;            // wave row (0..1)
    const int wn   = wave >> 1;           // wave col (0..1)
    const int g    = lane >> 4;           // quad  (0..3)
    const int m15  = lane & 15;

    if (tid < BM) { rs[tid] = 0.f; cs[tid] = 0.f; }

    // ---- staging addresses (computed once) ----
    // issue t in {0,1}: lane l covers LDS row r = wave*32 + t*16 + (l>>2),
    // lds chunk c' = l&3; swizzled source chunk c = (l&3) ^ ((l>>3)&3)
    // (since ((r>>1)&3) == ((l>>3)&3) for this layout).
    const int st_r0  = wave * 32 + (lane >> 2);            // t=0 row
    const int st_c   = (lane & 3) ^ ((lane >> 3) & 3);     // source chunk
    const __hip_bfloat16* gA0 = Z + (size_t)(bi * BM + st_r0) * HDIM + st_c * 8;
    const __hip_bfloat16* gA1 = gA0 + 16 * HDIM;           // t=1 rows
    const __hip_bfloat16* gB0 = Z + (size_t)(bj * BM + st_r0) * HDIM + st_c * 8;
    const __hip_bfloat16* gB1 = gB0 + 16 * HDIM;
    // wave-uniform LDS bases for the 4 issues (lane scatter is +l*16)
    __hip_bfloat16* lA0 = tA + (wave * 32) * BK;
    __hip_bfloat16* lA1 = tA + (wave * 32 + 16) * BK;
    __hip_bfloat16* lB0 = tB + (wave * 32) * BK;
    __hip_bfloat16* lB1 = tB + (wave * 32 + 16) * BK;

    // ---- fragment read addresses (computed once; all offsets imm) ----
    // row ra = wm*64 + f*16 + m15; k-chunk g swizzled by ((m15>>1)&3).
    const int sw = g ^ ((m15 >> 1) & 3);
    const __hip_bfloat16* rA = tA + (wm * 64 + m15) * BK + sw * 8;
    const __hip_bfloat16* rB = tB + (wn * 64 + m15) * BK + sw * 8;

    floatx4 acc[4][4] = {};

    // chunk ck global offset = ck*BK elements (folds to insn imm offset)
    #define STAGE(ck, buf)  do {                                            \
        async_copy16(gA0 + (ck) * BK, lA0 + (buf) * BM * BK);               \
        async_copy16(gA1 + (ck) * BK, lA1 + (buf) * BM * BK);               \
        async_copy16(gB0 + (ck) * BK, lB0 + (buf) * BM * BK);               \
        async_copy16(gB1 + (ck) * BK, lB1 + (buf) * BM * BK);               \
    } while (0)

    STAGE(0, 0);   // prologue

    #pragma unroll
    for (int ck = 0; ck < NCHUNK; ++ck) {
        const int cur = ck & 1;
        if (ck + 1 < NCHUNK) { STAGE(ck + 1, cur ^ 1); WAIT_VM4(); }
        else                 { WAIT_VM0(); }
        RAW_BARRIER();

        shortx8 af[4], bfr[4];
        #pragma unroll
        for (int f = 0; f < 4; ++f) {
            af[f]  = *(const shortx8*)(rA + cur * BM * BK + f * 16 * BK);
            bfr[f] = *(const shortx8*)(rB + cur * BM * BK + f * 16 * BK);
        }
        #pragma unroll
        for (int fm = 0; fm < 4; ++fm)
            #pragma unroll
            for (int fn = 0; fn < 4; ++fn)
                acc[fm][fn] = __builtin_amdgcn_mfma_f32_16x16x32_bf16(
                    af[fm], bfr[fn], acc[fm][fn], 0, 0, 0);

        WAIT_LGKM0();    // all ds_reads of this buffer complete
        RAW_BARRIER();   // WAR: before any wave's next stage overwrites
    }
    #undef STAGE

    // ---- epilogue: e = exp2(acc) (== exp(sim/tau)), reduce rows & cols ----
    float rp[4][4] = {{0.f}};  // [fm][reg] partial row sums
    float cp[4]    = {0.f};    // [fn]      partial col sums

    if (!diag) {
        #pragma unroll
        for (int fm = 0; fm < 4; ++fm)
            #pragma unroll
            for (int fn = 0; fn < 4; ++fn) {
                const floatx4 a = acc[fm][fn];
                #pragma unroll
                for (int q = 0; q < 4; ++q) {
                    const float e = __builtin_amdgcn_exp2f(a[q]);
                    rp[fm][q] += e;
                    cp[fn]    += e;
                }
            }
    } else {
        #pragma unroll
        for (int fm = 0; fm < 4; ++fm)
            #pragma unroll
            for (int fn = 0; fn < 4; ++fn) {
                const floatx4 a = acc[fm][fn];
                const int cl = wn * 64 + fn * 16 + m15;
                #pragma unroll
                for (int q = 0; q < 4; ++q) {
                    const int rl = wm * 64 + fm * 16 + g * 4 + q;
                    float e = __builtin_amdgcn_exp2f(a[q]);
                    if (cl <= rl) e = 0.f;   // strictly-upper only
                    rp[fm][q] += e;
                    cp[fn]    += e;
                }
            }
    }

    // row sums: reduce across the 16 lanes sharing a quad (same rows)
    #pragma unroll
    for (int mask = 1; mask < 16; mask <<= 1)
        #pragma unroll
        for (int fm = 0; fm < 4; ++fm)
            #pragma unroll
            for (int q = 0; q < 4; ++q)
                rp[fm][q] += __shfl_xor(rp[fm][q], mask);
    if (m15 == 0) {
        #pragma unroll
        for (int fm = 0; fm < 4; ++fm)
            #pragma unroll
            for (int q = 0; q < 4; ++q)
                atomicAdd(&rs[wm * 64 + fm * 16 + g * 4 + q], rp[fm][q]);
    }

    // col sums: reduce across quads (same cols)
    #pragma unroll
    for (int mask = 16; mask < 64; mask <<= 1)
        #pragma unroll
        for (int fn = 0; fn < 4; ++fn)
            cp[fn] += __shfl_xor(cp[fn], mask);
    if (g == 0) {
        #pragma unroll
        for (int fn = 0; fn < 4; ++fn)
            atomicAdd(&cs[wn * 64 + fn * 16 + m15], cp[fn]);
    }

    __syncthreads();
    if (tid < BM) {
        atomicAdd(&rowsum[(size_t)bi * BM + tid], rs[tid]);
        atomicAdd(&rowsum[(size_t)bj * BM + tid], cs[tid]);
    }

    // ---- last-finisher block computes the final loss (saves a dispatch) ----
    __shared__ int isLast;
    __threadfence();                 // drain our rowsum atomics
    __syncthreads();                 // all threads' atomics issued+fenced
    if (tid == 0) {
        const int t = __hip_atomic_fetch_add(counter, 1, __ATOMIC_ACQ_REL,
                                             __HIP_MEMORY_SCOPE_AGENT);
        isLast = (t == NBLK - 1);
    }
    __syncthreads();
    if (!isLast) return;

    float s = 0.f;
    for (int i = tid; i < N2; i += 256) {
        // atomic read-through: coherent vs other XCDs' atomics
        const float r = __hip_atomic_fetch_add(&rowsum[i], 0.0f,
                                               __ATOMIC_RELAXED,
                                               __HIP_MEMORY_SCOPE_AGENT);
        s += logf(r) - 2.0f * pos[i];
    }
    #pragma unroll
    for (int m = 1; m < 64; m <<= 1) s += __shfl_xor(s, m);
    if (lane == 0) rs[wave] = s;
    __syncthreads();
    if (tid == 0)
        out[0] = (rs[0] + rs[1] + rs[2] + rs[3]) / (float)N2;
}

// ---------------------------------------------------------------------------
extern "C" void kernel_launch(void* const* d_in, const int* in_sizes, int n_in,
                              void* d_out, int out_size, void* d_ws, size_t ws_size,
                              hipStream_t stream)
{
    const float* x = (const float*)d_in[0];
    const float* y = (const float*)d_in[1];

    // workspace: Z bf16 [16384*256] (8 MB) | rowsum f32 [16384] | pos f32 [16384] | counter
    __hip_bfloat16* Z = (__hip_bfloat16*)d_ws;
    float* rowsum = (float*)((char*)d_ws + (size_t)N2 * HDIM * sizeof(__hip_bfloat16));
    float* pos    = rowsum + N2;
    int*   counter = (int*)(pos + N2);

    normalize_kernel<<<NROWS / 4, 256, 0, stream>>>(x, y, Z, pos, rowsum, counter);
    simgemm_kernel<<<NBLK, 256, 0, stream>>>(Z, rowsum, pos, counter, (float*)d_out);
}

// Round 6
// 179.935 us; speedup vs baseline: 4.7776x; 4.7776x over previous
//
#include <hip/hip_runtime.h>
#include <hip/hip_bf16.h>
#include <math.h>

// Problem constants (fixed by reference setup_inputs)
constexpr int NROWS = 8192;   // B
constexpr int HDIM  = 256;    // H (= K of the GEMM)
constexpr int N2    = 16384;  // 2*B rows of Z
constexpr int BM    = 128;    // tile M = tile N
constexpr int BK    = 32;     // K chunk staged per round (8 chunks)
constexpr int NCHUNK = HDIM / BK;     // 8
constexpr int NTILE = N2 / BM;        // 128 tile-rows
constexpr int NBLK  = NTILE * (NTILE + 1) / 2;  // 8256 upper-tri tiles

// sqrt(2 * log2(e)): Z pre-scaled so Zs_i.Zs_j = 2*log2(e)*cos and
// exp2(acc) == exp(sim/tau), tau = 0.5
constexpr float PRESCALE = 1.69864357f;

typedef __attribute__((ext_vector_type(4))) float floatx4;
typedef __attribute__((ext_vector_type(8))) short shortx8; // 8 bf16 = 4 VGPRs

// offset must be a literal; constant pointer adds fold into the insn's
// immediate offset field after unrolling.
__device__ __forceinline__ void async_copy16(const void* gptr, void* lptr) {
    __builtin_amdgcn_global_load_lds(
        (const __attribute__((address_space(1))) unsigned int*)gptr,
        (__attribute__((address_space(3))) unsigned int*)lptr, 16, 0, 0);
}

// s_waitcnt immediates (gfx9: vm[3:0], exp[6:4], lgkm[11:8], vm-hi[15:14])
#define WAIT_VM4()   __builtin_amdgcn_s_waitcnt(0x0F74)  // vmcnt(4), others free
#define WAIT_VM0()   __builtin_amdgcn_s_waitcnt(0x0F70)  // vmcnt(0), others free
#define WAIT_LGKM0() __builtin_amdgcn_s_waitcnt(0xC07F)  // lgkmcnt(0), vm free
#define MEMFENCE()   __asm__ __volatile__("" ::: "memory")
#define RAW_BARRIER() do { MEMFENCE(); __builtin_amdgcn_s_barrier(); MEMFENCE(); } while (0)

// ---------------------------------------------------------------------------
// Kernel 1: wave-per-row L2-normalize -> bf16 Z (pre-scaled); pos = cos(x,y).
// Also zeroes rowsum and out (stream-ordered before consumers).
// ---------------------------------------------------------------------------
__global__ __launch_bounds__(256) void normalize_kernel(
    const float* __restrict__ x, const float* __restrict__ y,
    __hip_bfloat16* __restrict__ Z, float* __restrict__ pos,
    float* __restrict__ rowsum, float* __restrict__ out)
{
    const int wave = threadIdx.x >> 6, lane = threadIdx.x & 63;
    const int row  = blockIdx.x * 4 + wave;           // grid 2048 -> 8192 rows

    const float4 xv = ((const float4*)x)[row * 64 + lane];
    const float4 yv = ((const float4*)y)[row * 64 + lane];

    float sx  = xv.x*xv.x + xv.y*xv.y + xv.z*xv.z + xv.w*xv.w;
    float sy  = yv.x*yv.x + yv.y*yv.y + yv.z*yv.z + yv.w*yv.w;
    float sxy = xv.x*yv.x + xv.y*yv.y + xv.z*yv.z + xv.w*yv.w;
    #pragma unroll
    for (int m = 1; m < 64; m <<= 1) {
        sx  += __shfl_xor(sx,  m);
        sy  += __shfl_xor(sy,  m);
        sxy += __shfl_xor(sxy, m);
    }
    const float rxn = rsqrtf(sx), ryn = rsqrtf(sy);
    const float rx = rxn * PRESCALE, ry = ryn * PRESCALE;

    union { ushort4 u; __hip_bfloat16 h[4]; } zx, zy;
    zx.h[0] = __float2bfloat16(xv.x * rx); zx.h[1] = __float2bfloat16(xv.y * rx);
    zx.h[2] = __float2bfloat16(xv.z * rx); zx.h[3] = __float2bfloat16(xv.w * rx);
    zy.h[0] = __float2bfloat16(yv.x * ry); zy.h[1] = __float2bfloat16(yv.y * ry);
    zy.h[2] = __float2bfloat16(yv.z * ry); zy.h[3] = __float2bfloat16(yv.w * ry);
    ((ushort4*)Z)[row * 64 + lane]             = zx.u;
    ((ushort4*)Z)[(row + NROWS) * 64 + lane]   = zy.u;

    if (lane == 0) {
        const float p = sxy * rxn * ryn;
        pos[row]         = p;
        pos[row + NROWS] = p;
    }
    const int gt = blockIdx.x * 256 + threadIdx.x;
    if (gt < N2) rowsum[gt] = 0.f;
    if (gt == 0) out[0] = 0.f;
}

// ---------------------------------------------------------------------------
// Kernel 2: upper-triangle tiled Z·Z^T, fused exp2 + row/col sums.
// BK=32 double-buffered staging: LDS = 33 KB -> 4 blocks/CU (16 waves) AND
// prefetch via raw barrier + vmcnt(4) (next chunk's 4 loads stay in flight
// across the barrier). All offsets compile-time immediates off per-lane bases.
// NO device-scope fences/acq-rel anywhere in this kernel: R5 showed a
// per-block __threadfence + ACQ_REL RMW lowers to L2 wb/inv on gfx950 and
// collapses achieved fetch BW to ~200 GB/s (825 us). Final reduction is a
// separate kernel instead.
// LDS tile layout: row-major [128][32] bf16 per tile; 16B chunk c of row r
// stored at chunk c ^ ((r>>1)&3)  (frag reads then 2-way max = free).
// ---------------------------------------------------------------------------
__global__ __launch_bounds__(256, 4) void simgemm_kernel(
    const __hip_bfloat16* __restrict__ Z, float* __restrict__ rowsum)
{
    // linear -> (bi, bj) upper-triangle mapping; cum(bi) = bi*(257-bi)/2
    const int b = blockIdx.x;
    int bi = (int)((257.0f - sqrtf(66049.0f - 8.0f * (float)b)) * 0.5f);
    int cum = bi * (257 - bi) / 2;
    if (b < cum)      { bi--; cum = bi * (257 - bi) / 2; }
    else { const int cn = (bi + 1) * (256 - bi) / 2;
           if (b >= cn) { bi++; cum = cn; } }
    const int bj = bi + (b - cum);
    const bool diag = (bi == bj);

    // contiguous LDS: tA[2] | tB[2] (8 KB each) | rs | cs
    __shared__ alignas(16) __hip_bfloat16 tiles[4 * BM * BK];  // 32 KB
    __shared__ float rs[BM];
    __shared__ float cs[BM];
    __hip_bfloat16* tA = tiles;                 // +0, buf1 at +8192 B
    __hip_bfloat16* tB = tiles + 2 * BM * BK;   // +16384 B, buf1 +24576 B

    const int tid  = threadIdx.x;
    const int wave = tid >> 6;
    const int lane = tid & 63;
    const int wm   = wave & 1;            // wave row (0..1)
    const int wn   = wave >> 1;           // wave col (0..1)
    const int g    = lane >> 4;           // quad  (0..3)
    const int m15  = lane & 15;

    if (tid < BM) { rs[tid] = 0.f; cs[tid] = 0.f; }

    // ---- staging addresses (computed once) ----
    // issue t in {0,1}: lane l covers LDS row r = wave*32 + t*16 + (l>>2),
    // lds chunk c' = l&3; swizzled source chunk c = (l&3) ^ ((l>>3)&3).
    const int st_r0  = wave * 32 + (lane >> 2);            // t=0 row
    const int st_c   = (lane & 3) ^ ((lane >> 3) & 3);     // source chunk
    const __hip_bfloat16* gA0 = Z + (size_t)(bi * BM + st_r0) * HDIM + st_c * 8;
    const __hip_bfloat16* gA1 = gA0 + 16 * HDIM;           // t=1 rows
    const __hip_bfloat16* gB0 = Z + (size_t)(bj * BM + st_r0) * HDIM + st_c * 8;
    const __hip_bfloat16* gB1 = gB0 + 16 * HDIM;
    // wave-uniform LDS bases for the 4 issues (lane scatter is +l*16)
    __hip_bfloat16* lA0 = tA + (wave * 32) * BK;
    __hip_bfloat16* lA1 = tA + (wave * 32 + 16) * BK;
    __hip_bfloat16* lB0 = tB + (wave * 32) * BK;
    __hip_bfloat16* lB1 = tB + (wave * 32 + 16) * BK;

    // ---- fragment read addresses (computed once; all offsets imm) ----
    // row ra = wm*64 + f*16 + m15; k-chunk g swizzled by ((m15>>1)&3).
    const int sw = g ^ ((m15 >> 1) & 3);
    const __hip_bfloat16* rA = tA + (wm * 64 + m15) * BK + sw * 8;
    const __hip_bfloat16* rB = tB + (wn * 64 + m15) * BK + sw * 8;

    floatx4 acc[4][4] = {};

    // chunk ck global offset = ck*BK elements (folds to insn imm offset)
    #define STAGE(ck, buf)  do {                                            \
        async_copy16(gA0 + (ck) * BK, lA0 + (buf) * BM * BK);               \
        async_copy16(gA1 + (ck) * BK, lA1 + (buf) * BM * BK);               \
        async_copy16(gB0 + (ck) * BK, lB0 + (buf) * BM * BK);               \
        async_copy16(gB1 + (ck) * BK, lB1 + (buf) * BM * BK);               \
    } while (0)

    STAGE(0, 0);   // prologue

    #pragma unroll
    for (int ck = 0; ck < NCHUNK; ++ck) {
        const int cur = ck & 1;
        if (ck + 1 < NCHUNK) { STAGE(ck + 1, cur ^ 1); WAIT_VM4(); }
        else                 { WAIT_VM0(); }
        RAW_BARRIER();

        shortx8 af[4], bfr[4];
        #pragma unroll
        for (int f = 0; f < 4; ++f) {
            af[f]  = *(const shortx8*)(rA + cur * BM * BK + f * 16 * BK);
            bfr[f] = *(const shortx8*)(rB + cur * BM * BK + f * 16 * BK);
        }
        #pragma unroll
        for (int fm = 0; fm < 4; ++fm)
            #pragma unroll
            for (int fn = 0; fn < 4; ++fn)
                acc[fm][fn] = __builtin_amdgcn_mfma_f32_16x16x32_bf16(
                    af[fm], bfr[fn], acc[fm][fn], 0, 0, 0);

        WAIT_LGKM0();    // all ds_reads of this buffer complete
        RAW_BARRIER();   // WAR: before any wave's next stage overwrites
    }
    #undef STAGE

    // ---- epilogue: e = exp2(acc) (== exp(sim/tau)), reduce rows & cols ----
    float rp[4][4] = {{0.f}};  // [fm][reg] partial row sums
    float cp[4]    = {0.f};    // [fn]      partial col sums

    if (!diag) {
        #pragma unroll
        for (int fm = 0; fm < 4; ++fm)
            #pragma unroll
            for (int fn = 0; fn < 4; ++fn) {
                const floatx4 a = acc[fm][fn];
                #pragma unroll
                for (int q = 0; q < 4; ++q) {
                    const float e = __builtin_amdgcn_exp2f(a[q]);
                    rp[fm][q] += e;
                    cp[fn]    += e;
                }
            }
    } else {
        #pragma unroll
        for (int fm = 0; fm < 4; ++fm)
            #pragma unroll
            for (int fn = 0; fn < 4; ++fn) {
                const floatx4 a = acc[fm][fn];
                const int cl = wn * 64 + fn * 16 + m15;
                #pragma unroll
                for (int q = 0; q < 4; ++q) {
                    const int rl = wm * 64 + fm * 16 + g * 4 + q;
                    float e = __builtin_amdgcn_exp2f(a[q]);
                    if (cl <= rl) e = 0.f;   // strictly-upper only
                    rp[fm][q] += e;
                    cp[fn]    += e;
                }
            }
    }

    // row sums: reduce across the 16 lanes sharing a quad (same rows)
    #pragma unroll
    for (int mask = 1; mask < 16; mask <<= 1)
        #pragma unroll
        for (int fm = 0; fm < 4; ++fm)
            #pragma unroll
            for (int q = 0; q < 4; ++q)
                rp[fm][q] += __shfl_xor(rp[fm][q], mask);
    if (m15 == 0) {
        #pragma unroll
        for (int fm = 0; fm < 4; ++fm)
            #pragma unroll
            for (int q = 0; q < 4; ++q)
                atomicAdd(&rs[wm * 64 + fm * 16 + g * 4 + q], rp[fm][q]);
    }

    // col sums: reduce across quads (same cols)
    #pragma unroll
    for (int mask = 16; mask < 64; mask <<= 1)
        #pragma unroll
        for (int fn = 0; fn < 4; ++fn)
            cp[fn] += __shfl_xor(cp[fn], mask);
    if (g == 0) {
        #pragma unroll
        for (int fn = 0; fn < 4; ++fn)
            atomicAdd(&cs[wn * 64 + fn * 16 + m15], cp[fn]);
    }

    __syncthreads();
    if (tid < BM) {
        atomicAdd(&rowsum[(size_t)bi * BM + tid], rs[tid]);
        atomicAdd(&rowsum[(size_t)bj * BM + tid], cs[tid]);
    }
}

// ---------------------------------------------------------------------------
// Kernel 3: loss = mean( log(rowsum_i) - 2*pos_i ), 16 blocks + atomic.
// out[0] zeroed by normalize_kernel (stream-ordered).
// ---------------------------------------------------------------------------
__global__ __launch_bounds__(1024) void finalize_kernel(
    const float* __restrict__ rowsum, const float* __restrict__ pos,
    float* __restrict__ out)
{
    const int i = threadIdx.x + blockIdx.x * 1024;
    float s = logf(rowsum[i]) - 2.0f * pos[i];
    #pragma unroll
    for (int off = 32; off; off >>= 1) s += __shfl_down(s, off);
    __shared__ float sh[16];
    const int lt = threadIdx.x;
    if ((lt & 63) == 0) sh[lt >> 6] = s;
    __syncthreads();
    if (lt == 0) {
        float tot = 0.f;
        #pragma unroll
        for (int w = 0; w < 16; ++w) tot += sh[w];
        atomicAdd(out, tot / (float)N2);
    }
}

// ---------------------------------------------------------------------------
extern "C" void kernel_launch(void* const* d_in, const int* in_sizes, int n_in,
                              void* d_out, int out_size, void* d_ws, size_t ws_size,
                              hipStream_t stream)
{
    const float* x = (const float*)d_in[0];
    const float* y = (const float*)d_in[1];

    // workspace: Z bf16 [16384*256] (8 MB) | rowsum f32 [16384] | pos f32 [16384]
    __hip_bfloat16* Z = (__hip_bfloat16*)d_ws;
    float* rowsum = (float*)((char*)d_ws + (size_t)N2 * HDIM * sizeof(__hip_bfloat16));
    float* pos    = rowsum + N2;

    normalize_kernel<<<NROWS / 4, 256, 0, stream>>>(x, y, Z, pos, rowsum, (float*)d_out);
    simgemm_kernel<<<NBLK, 256, 0, stream>>>(Z, rowsum);
    finalize_kernel<<<N2 / 1024, 1024, 0, stream>>>(rowsum, pos, (float*)d_out);
}